// Round 12
// baseline (148.674 us; speedup 1.0000x reference)
//
#include <hip/hip_runtime.h>
#include <cstdint>

#pragma clang fp contract(off)

#define NB      32
#define NC      18
#define NA      8400
#define NCH     (4 + NC)
#define NTASK   (NB * NC)      // 576
#define TOPK    300
#define TARGET  316        // TOPK + margin: absorbs sigmoid-tie rank ambiguity
#define NBINS   2048
#define CAP     1024
#define CONF    0.25f
#define IOU_T   0.45f
#define NT      512
#define NW      (NT / 64)
// Prefilter: N(0,1) logits, top-316 cutoff ~1.75 +- 0.1; count(x>1.4) in [553,803] (5-sigma).
// Fast path requires TARGET <= s_cnt <= CAP, else exact fallback.
#define PREF_X  1.4f
// sigmoid(x) > 0.25  <=>  x > -ln(3). Outside [XLO,XHI] analytic compare is exact.
#define XHI     (-1.0984f)
#define XLO     (-1.0988f)

// Fast-path binning: keys (mono_key of x>1.4) start at 0xBFB33333.
#define FAST_KBASE 0xBFB00000u
#define FAST_SHIFT 14
// Fallback binning: conf_pass keys start ~0x40735C26.
#define FB_KBASE   0x40000000u
#define FB_SHIFT   21

// Exact div-free IoU compare: RN_f32(inter/D) > 0.45f  <=>  inter > M45*D.
// M45 = fp32(0.45) + 2^-26 (25-bit mantissa, exact in f64; x 24-bit D -> exact
// 49-bit product). Tie rounds-to-even back to 0.45f => not >, matching. Bit-exact.
#define M45 (30198989.0 / 67108864.0)

// Workspace layout (10.37 MB):
#define WS_BOX 0                                  // float4[576][300]  2764800 B
#define WS_VAL (NTASK * TOPK * 16)                // float [576][300]   691200 B
#define WS_SUP (WS_VAL + NTASK * TOPK * 4)        // ull   [576][300][5] 6912000 B
#define WS_CNT (WS_SUP + NTASK * TOPK * 5 * 8)    // int   [576]          2304 B

typedef unsigned long long ull;

__device__ __forceinline__ float sigmoidf(float x) {
    return 1.0f / (1.0f + expf(-x));
}
__device__ __forceinline__ unsigned int mono_key(unsigned int bits) {
    return (bits & 0x80000000u) ? ~bits : (bits | 0x80000000u);
}
__device__ __forceinline__ unsigned int mono_inv(unsigned int key) {
    return (key & 0x80000000u) ? (key ^ 0x80000000u) : ~key;
}
__device__ __forceinline__ bool conf_pass(float x) {
    if (x >= XHI) return true;
    if (x <= XLO) return false;
    return sigmoidf(x) > CONF;   // rare exact band (~1 element per task)
}
__device__ __forceinline__ unsigned int make_key(float x) {
    return conf_pass(x) ? mono_key(__float_as_uint(x)) : 0u;
}
__device__ __forceinline__ ull readlane64(ull v, int i) {
    unsigned lo = (unsigned)__builtin_amdgcn_readlane((int)(unsigned)(v & 0xFFFFFFFFull), i);
    unsigned hi = (unsigned)__builtin_amdgcn_readlane((int)(unsigned)(v >> 32), i);
    return ((ull)hi << 32) | (ull)lo;
}

// Suffix-find over hist: T1 s.t. count(bins > T1) < target <= count(bins >= T1).
__device__ __forceinline__ void suffix_find(unsigned int* hist, unsigned int* wtot,
                                            int target, int tid, int* s_T1) {
    const int base = tid * (NBINS / NT);
    unsigned int v = 0;
#pragma unroll
    for (int k = 0; k < NBINS / NT; ++k) v += hist[base + k];
    const int lane = tid & 63;
    unsigned int s = v;
#pragma unroll
    for (int d = 1; d < 64; d <<= 1) {
        unsigned int o = __shfl_down(s, d, 64);
        if (lane + d < 64) s += o;
    }
    if (lane == 0) wtot[tid >> 6] = s;
    __syncthreads();
    unsigned int above_waves = 0;
    for (int wv = (tid >> 6) + 1; wv < NW; ++wv) above_waves += wtot[wv];
    unsigned int acc = (s - v) + above_waves;
    for (int bin = base + (NBINS / NT) - 1; bin >= base; --bin) {
        unsigned int cnt = hist[bin];
        if (acc < (unsigned int)target && acc + cnt >= (unsigned int)target) *s_T1 = bin;
        acc += cnt;
    }
    __syncthreads();
}

// K1 LDS: [0,8192) hist -> cand2 ; [8192,16384) cand
#define OFF_CAND   8192
#define POOL1_BYTES 16384

// ============ K1: top-300 select (per task), gather fused into rank write ============
__global__ __launch_bounds__(NT) void k_select(const float* __restrict__ in,
                                               float4* __restrict__ wsBox,
                                               float* __restrict__ wsVal,
                                               int* __restrict__ wsCnt) {
    __shared__ __align__(16) unsigned char pool[POOL1_BYTES];
    __shared__ unsigned int wtot[NW];
    __shared__ unsigned int s_cnt, s_cnt2;
    __shared__ int s_T1;

    unsigned int* hist = (unsigned int*)pool;
    ull* cand2 = (ull*)pool;
    ull* cand  = (ull*)(pool + OFF_CAND);

    const int tid = threadIdx.x;
    const int lane = tid & 63;
    const ull ltm = (1ull << lane) - 1ull;
    const int t = blockIdx.x;
    // XCD swizzle: image b -> XCD b%8
    const int b = (t & 7) + 8 * ((t >> 3) & 3);
    const int c = t >> 5;
    const float* cls = in + (size_t)b * NCH * NA + (size_t)(4 + c) * NA;
    const float* box = in + (size_t)b * NCH * NA;

    for (int i = tid; i < NBINS; i += NT) hist[i] = 0;
    if (tid == 0) { s_cnt = 0; s_cnt2 = 0; s_T1 = -1; }
    __syncthreads();

    // P1: prefilter x>1.4, wave-aggregated compaction, fused refine histogram
    {
        const float4* cls4 = (const float4*)cls;
        for (int q = tid; q < NA / 4; q += NT) {
            float4 v = cls4[q];
            const unsigned int i0 = (unsigned int)q * 4u;
            float xs[4] = {v.x, v.y, v.z, v.w};
            ull m[4];
            unsigned int cnt = 0;
#pragma unroll
            for (int u = 0; u < 4; ++u) {
                m[u] = __ballot(xs[u] > PREF_X);
                cnt += (unsigned int)__popcll(m[u]);
            }
            if (cnt) {
                unsigned int base = 0;
                if (lane == 0) base = atomicAdd(&s_cnt, cnt);
                base = (unsigned int)__builtin_amdgcn_readfirstlane((int)base);
                unsigned int pre = 0;
#pragma unroll
                for (int u = 0; u < 4; ++u) {
                    if (xs[u] > PREF_X) {
                        unsigned int mk = mono_key(__float_as_uint(xs[u]));
                        atomicAdd(&hist[min((mk - FAST_KBASE) >> FAST_SHIFT,
                                            (unsigned)(NBINS - 1))], 1u);
                        unsigned int p = base + pre + (unsigned int)__popcll(m[u] & ltm);
                        if (p < CAP)
                            cand[p] = ((ull)mk << 32) | (ull)(~(i0 + u));
                    }
                    pre += (unsigned int)__popcll(m[u]);
                }
            }
        }
    }
    __syncthreads();

    const int pcnt = (int)s_cnt;
    if (pcnt >= TARGET && pcnt <= CAP) {
        // ---- fast path ----
        suffix_find(hist, wtot, TARGET, tid, &s_T1);
        const ull thr = ((ull)FAST_KBASE + ((ull)(unsigned int)s_T1 << FAST_SHIFT)) << 32;
        const int iters = (pcnt + NT - 1) / NT;
        for (int it = 0; it < iters; ++it) {
            int e = tid + it * NT;
            bool act = e < pcnt;
            ull k = act ? cand[e] : 0ull;
            bool sel = act && (k >= thr);
            ull mb = __ballot(sel);
            unsigned int cnt = (unsigned int)__popcll(mb);
            if (cnt) {
                unsigned int basep = 0;
                if (lane == 0) basep = atomicAdd(&s_cnt2, cnt);
                basep = (unsigned int)__builtin_amdgcn_readfirstlane((int)basep);
                if (sel) {
                    float xv = __uint_as_float(mono_inv((unsigned int)(k >> 32)));
                    float sv = sigmoidf(xv);
                    unsigned int p = basep + (unsigned int)__popcll(mb & ltm);
                    if (p < CAP)
                        cand2[p] = ((ull)__float_as_uint(sv) << 32) | (k & 0xFFFFFFFFull);
                }
            }
        }
        __syncthreads();
    } else {
        // ---- exact fallback (rare): re-zero hist, full conf_pass histogram ----
        __syncthreads();
        for (int i = tid; i < NBINS; i += NT) hist[i] = 0;
        __syncthreads();
        {
            const float4* cls4 = (const float4*)cls;
            for (int q = tid; q < NA / 4; q += NT) {
                float4 v = cls4[q];
                unsigned int kx = make_key(v.x), ky = make_key(v.y);
                unsigned int kz = make_key(v.z), kw = make_key(v.w);
                if (kx) atomicAdd(&hist[min((kx - FB_KBASE) >> FB_SHIFT, (unsigned)(NBINS - 1))], 1u);
                if (ky) atomicAdd(&hist[min((ky - FB_KBASE) >> FB_SHIFT, (unsigned)(NBINS - 1))], 1u);
                if (kz) atomicAdd(&hist[min((kz - FB_KBASE) >> FB_SHIFT, (unsigned)(NBINS - 1))], 1u);
                if (kw) atomicAdd(&hist[min((kw - FB_KBASE) >> FB_SHIFT, (unsigned)(NBINS - 1))], 1u);
            }
        }
        __syncthreads();
        suffix_find(hist, wtot, TARGET, tid, &s_T1);
        {
            const ull thr = (s_T1 < 0) ? 0ull
                : ((ull)FB_KBASE + ((ull)(unsigned int)s_T1 << FB_SHIFT));
            const float4* cls4 = (const float4*)cls;
            for (int q = tid; q < NA / 4; q += NT) {
                float4 v = cls4[q];
                const unsigned int i0 = (unsigned int)q * 4u;
                float xs[4] = {v.x, v.y, v.z, v.w};
#pragma unroll
                for (int u = 0; u < 4; ++u) {
                    unsigned int d = make_key(xs[u]);
                    if (d && (ull)d >= thr) {
                        unsigned int p = atomicAdd(&s_cnt2, 1u);
                        if (p < CAP) {
                            float sv = sigmoidf(xs[u]);
                            cand2[p] = ((ull)__float_as_uint(sv) << 32) | (ull)(~(i0 + u));
                        }
                    }
                }
            }
        }
        __syncthreads();
    }

    const int F = min((int)s_cnt2, CAP);
    const int numSel = min(F, TOPK);

    // rank-by-counting (unique keys via ~idx) + FUSED box gather to ws
    float4* tBox = wsBox + (size_t)t * TOPK;
    float*  tVal = wsVal + (size_t)t * TOPK;
    for (int e = tid; e < F; e += NT) {
        ull k = cand2[e];
        int rank = 0;
        int o = 0;
#pragma unroll 2
        for (; o + 4 <= F; o += 4) {
            ulonglong2 p0 = *(const ulonglong2*)&cand2[o];
            ulonglong2 p1 = *(const ulonglong2*)&cand2[o + 2];
            rank += (p0.x > k) + (p0.y > k) + (p1.x > k) + (p1.y > k);
        }
        for (; o < F; ++o) rank += (cand2[o] > k) ? 1 : 0;
        if (rank < TOPK) {
            unsigned int i = ~(unsigned int)(k & 0xFFFFFFFFull);
            float cx = box[i];
            float cy = box[NA + i];
            float w  = box[2 * NA + i];
            float h  = box[3 * NA + i];
            float hw = w * 0.5f, hh = h * 0.5f;
            tBox[rank] = float4{cx - hw, cy - hh, cx + hw, cy + hh};
            tVal[rank] = __uint_as_float((unsigned int)(k >> 32));
        }
    }
    if (tid == 0) wsCnt[t] = numSel;
}

// ============ K2: suppression-mask build, 2880 uniform blocks ============
__global__ __launch_bounds__(256) void k_mask(const float4* __restrict__ wsBox,
                                              const int* __restrict__ wsCnt,
                                              ull* __restrict__ wsSup) {
    const int t = blockIdx.x;
    const int g = blockIdx.y;          // row group: rows [64g, 64g+64)
    const int tid = threadIdx.x;
    const int lane = tid & 63;
    const int wave = tid >> 6;

    __shared__ float4 bs[TOPK];
    __shared__ float  ar[TOPK];
    __shared__ int s_n;
    if (tid == 0) s_n = wsCnt[t];
    __syncthreads();
    const int numSel = s_n;

    const float4* tb = wsBox + (size_t)t * TOPK;
    for (int r = tid; r < TOPK; r += 256) {
        float4 v = (r < numSel) ? tb[r] : float4{0.f, 0.f, 0.f, 0.f};
        bs[r] = v;
        ar[r] = fmaxf(v.z - v.x, 0.f) * fmaxf(v.w - v.y, 0.f);
    }
    __syncthreads();

    float4 cb[5];
    float ca[5];
#pragma unroll
    for (int w = 0; w < 5; ++w) {
        int j = (w << 6) + lane;
        bool v = j < TOPK;
        cb[w] = v ? bs[j] : float4{0.f, 0.f, 0.f, 0.f};
        ca[w] = v ? ar[j] : 0.f;
    }

    const int r0 = g << 6;
    const int rend = min(r0 + 64, TOPK);
    ull* supt = wsSup + (size_t)t * (TOPK * 5);
    for (int r = r0 + wave; r < rend; r += 4) {
        const bool vrow = r < numSel;      // wave-uniform
        float4 bi = bs[r];
        float ai = ar[r];
#pragma unroll
        for (int w = 0; w < 5; ++w) {
            ull bal = 0ull;
            if (w >= g && vrow) {          // uniform branch
                const int j = (w << 6) + lane;
                bool supb = false;
                if (j < numSel && j > r) {
                    float xx1 = fmaxf(bi.x, cb[w].x);
                    float yy1 = fmaxf(bi.y, cb[w].y);
                    float xx2 = fminf(bi.z, cb[w].z);
                    float yy2 = fminf(bi.w, cb[w].w);
                    float iw = fmaxf(xx2 - xx1, 0.0f);
                    float ih = fmaxf(yy2 - yy1, 0.0f);
                    float inter = iw * ih;
                    float un = ai + ca[w] - inter;
                    float D = fmaxf(un, 1e-9f);
                    supb = (double)inter > M45 * (double)D;  // == RN(inter/D) > 0.45f
                }
                bal = __ballot(supb);
            }
            if (lane == 0) supt[r * 5 + w] = bal;
        }
    }
}

// ============ K3: greedy scan + output. Mask words in NAMED scalars (cannot
// silently spill, unlike the R11 a[5][5] array: VGPR=28 + 5.2 MB scratch
// traffic = 43 us). __launch_bounds__(64,1) allows the full VGPR budget. ====
__global__ __launch_bounds__(64, 1) void k_scan_out(const float4* __restrict__ wsBox,
                                                    const float* __restrict__ wsVal,
                                                    const int* __restrict__ wsCnt,
                                                    const ull* __restrict__ wsSup,
                                                    float* __restrict__ out) {
    const int t = blockIdx.x;
    const int lane = threadIdx.x;
    const int numSel = wsCnt[t];
    const ull* supt = wsSup + (size_t)t * (TOPK * 5);

    // Row r = 64*w + lane holds words x=0..4. Groups 0..3 always in range
    // (r <= 255 < 300); group 4 valid iff lane < 44.
    const ull* p0 = supt + (size_t)(lane) * 5;
    ull A00 = p0[0], A01 = p0[1], A02 = p0[2], A03 = p0[3], A04 = p0[4];
    const ull* p1 = supt + (size_t)(64 + lane) * 5;
    ull A10 = p1[0], A11 = p1[1], A12 = p1[2], A13 = p1[3], A14 = p1[4];
    const ull* p2 = supt + (size_t)(128 + lane) * 5;
    ull A20 = p2[0], A21 = p2[1], A22 = p2[2], A23 = p2[3], A24 = p2[4];
    const ull* p3 = supt + (size_t)(192 + lane) * 5;
    ull A30 = p3[0], A31 = p3[1], A32 = p3[2], A33 = p3[3], A34 = p3[4];
    const bool v4 = lane < (TOPK - 256);
    const ull* p4 = supt + (size_t)(256 + (v4 ? lane : 0)) * 5;
    ull A40 = v4 ? p4[0] : 0ull, A41 = v4 ? p4[1] : 0ull, A42 = v4 ? p4[2] : 0ull,
        A43 = v4 ? p4[3] : 0ull, A44 = v4 ? p4[4] : 0ull;

    ull rem0 = 0, rem1 = 0, rem2 = 0, rem3 = 0, rem4 = 0;
    {
        int n = min(numSel, 64);
        for (int i = 0; i < n; ++i)
            if (!((rem0 >> i) & 1ull)) {    // uniform: rem identical on all lanes
                rem0 |= readlane64(A00, i); rem1 |= readlane64(A01, i);
                rem2 |= readlane64(A02, i); rem3 |= readlane64(A03, i);
                rem4 |= readlane64(A04, i);
            }
    }
    {
        int n = min(max(numSel - 64, 0), 64);
        for (int i = 0; i < n; ++i)
            if (!((rem1 >> i) & 1ull)) {
                rem0 |= readlane64(A10, i); rem1 |= readlane64(A11, i);
                rem2 |= readlane64(A12, i); rem3 |= readlane64(A13, i);
                rem4 |= readlane64(A14, i);
            }
    }
    {
        int n = min(max(numSel - 128, 0), 64);
        for (int i = 0; i < n; ++i)
            if (!((rem2 >> i) & 1ull)) {
                rem0 |= readlane64(A20, i); rem1 |= readlane64(A21, i);
                rem2 |= readlane64(A22, i); rem3 |= readlane64(A23, i);
                rem4 |= readlane64(A24, i);
            }
    }
    {
        int n = min(max(numSel - 192, 0), 64);
        for (int i = 0; i < n; ++i)
            if (!((rem3 >> i) & 1ull)) {
                rem0 |= readlane64(A30, i); rem1 |= readlane64(A31, i);
                rem2 |= readlane64(A32, i); rem3 |= readlane64(A33, i);
                rem4 |= readlane64(A34, i);
            }
    }
    {
        int n = min(max(numSel - 256, 0), 64);
        for (int i = 0; i < n; ++i)
            if (!((rem4 >> i) & 1ull)) {
                rem0 |= readlane64(A40, i); rem1 |= readlane64(A41, i);
                rem2 |= readlane64(A42, i); rem3 |= readlane64(A43, i);
                rem4 |= readlane64(A44, i);
            }
    }

    const int b = (t & 7) + 8 * ((t >> 3) & 3);
    const int c = t >> 5;
    float* outp = out + ((size_t)b * NC + c) * (TOPK * 6);
    const float4* tb = wsBox + (size_t)t * TOPK;
    const float* tv = wsVal + (size_t)t * TOPK;

    auto write_row = [&](int w, ull remw) {
        int r = (w << 6) + lane;
        if (r < TOPK) {
            float x1 = 0.f, y1 = 0.f, x2 = 0.f, y2 = 0.f, vv = 0.f, cc = 0.f;
            if (r < numSel && ((~remw >> lane) & 1ull)) {
                float4 bb = tb[r];
                x1 = bb.x; y1 = bb.y; x2 = bb.z; y2 = bb.w;
                vv = tv[r]; cc = (float)c;
            }
            float* row = outp + r * 6;
            *(float2*)(row)     = float2{x1, y1};
            *(float2*)(row + 2) = float2{x2, y2};
            *(float2*)(row + 4) = float2{vv, cc};
        }
    };
    write_row(0, rem0);
    write_row(1, rem1);
    write_row(2, rem2);
    write_row(3, rem3);
    write_row(4, rem4);
}

extern "C" void kernel_launch(void* const* d_in, const int* in_sizes, int n_in,
                              void* d_out, int out_size, void* d_ws, size_t ws_size,
                              hipStream_t stream) {
    const float* in = (const float*)d_in[0];
    float* out = (float*)d_out;
    char* ws = (char*)d_ws;
    float4* wsBox = (float4*)(ws + WS_BOX);
    float*  wsVal = (float*)(ws + WS_VAL);
    ull*    wsSup = (ull*)(ws + WS_SUP);
    int*    wsCnt = (int*)(ws + WS_CNT);

    k_select<<<NTASK, NT, 0, stream>>>(in, wsBox, wsVal, wsCnt);
    k_mask<<<dim3(NTASK, 5), 256, 0, stream>>>(wsBox, wsCnt, wsSup);
    k_scan_out<<<NTASK, 64, 0, stream>>>(wsBox, wsVal, wsCnt, wsSup, out);
}

// Round 13
// 147.857 us; speedup vs baseline: 1.0055x; 1.0055x over previous
//
#include <hip/hip_runtime.h>
#include <cstdint>

#pragma clang fp contract(off)

#define NB      32
#define NC      18
#define NA      8400
#define NCH     (4 + NC)
#define NTASK   (NB * NC)      // 576
#define TOPK    300
#define TARGET  316        // TOPK + margin: absorbs sigmoid-tie rank ambiguity
#define NBINS   2048
#define CAP     1024
#define CONF    0.25f
#define IOU_T   0.45f
#define NT      512
#define NW      (NT / 64)
// Prefilter: N(0,1) logits, top-316 cutoff ~1.75 +- 0.1; count(x>1.4) in [553,803] (5-sigma).
// Fast path requires TARGET <= s_cnt <= CAP, else exact fallback.
#define PREF_X  1.4f
// sigmoid(x) > 0.25  <=>  x > -ln(3). Outside [XLO,XHI] analytic compare is exact.
#define XHI     (-1.0984f)
#define XLO     (-1.0988f)

// Fast-path binning: keys (mono_key of x>1.4) start at 0xBFB33333.
#define FAST_KBASE 0xBFB00000u
#define FAST_SHIFT 14
// Fallback binning: conf_pass keys start ~0x40735C26.
#define FB_KBASE   0x40000000u
#define FB_SHIFT   21

// Exact div-free IoU compare: RN_f32(inter/D) > 0.45f  <=>  inter > M45*D.
// M45 = fp32(0.45) + 2^-26 (25-bit mantissa, exact in f64; x 24-bit D -> exact
// 49-bit product). Tie rounds-to-even back to 0.45f => not >, matching. Bit-exact.
#define M45 (30198989.0 / 67108864.0)

// Workspace layout (10.37 MB):
#define WS_BOX 0                                  // float4[576][300]  2764800 B
#define WS_VAL (NTASK * TOPK * 16)                // float [576][300]   691200 B
#define WS_SUP (WS_VAL + NTASK * TOPK * 4)        // ull   [576][300][5] 6912000 B
#define WS_CNT (WS_SUP + NTASK * TOPK * 5 * 8)    // int   [576]          2304 B

typedef unsigned long long ull;

__device__ __forceinline__ float sigmoidf(float x) {
    return 1.0f / (1.0f + expf(-x));
}
__device__ __forceinline__ unsigned int mono_key(unsigned int bits) {
    return (bits & 0x80000000u) ? ~bits : (bits | 0x80000000u);
}
__device__ __forceinline__ unsigned int mono_inv(unsigned int key) {
    return (key & 0x80000000u) ? (key ^ 0x80000000u) : ~key;
}
__device__ __forceinline__ bool conf_pass(float x) {
    if (x >= XHI) return true;
    if (x <= XLO) return false;
    return sigmoidf(x) > CONF;   // rare exact band (~1 element per task)
}
__device__ __forceinline__ unsigned int make_key(float x) {
    return conf_pass(x) ? mono_key(__float_as_uint(x)) : 0u;
}
__device__ __forceinline__ ull readlane64(ull v, int i) {
    unsigned lo = (unsigned)__builtin_amdgcn_readlane((int)(unsigned)(v & 0xFFFFFFFFull), i);
    unsigned hi = (unsigned)__builtin_amdgcn_readlane((int)(unsigned)(v >> 32), i);
    return ((ull)hi << 32) | (ull)lo;
}

// Suffix-find over hist: T1 s.t. count(bins > T1) < target <= count(bins >= T1).
__device__ __forceinline__ void suffix_find(unsigned int* hist, unsigned int* wtot,
                                            int target, int tid, int* s_T1) {
    const int base = tid * (NBINS / NT);
    unsigned int v = 0;
#pragma unroll
    for (int k = 0; k < NBINS / NT; ++k) v += hist[base + k];
    const int lane = tid & 63;
    unsigned int s = v;
#pragma unroll
    for (int d = 1; d < 64; d <<= 1) {
        unsigned int o = __shfl_down(s, d, 64);
        if (lane + d < 64) s += o;
    }
    if (lane == 0) wtot[tid >> 6] = s;
    __syncthreads();
    unsigned int above_waves = 0;
    for (int wv = (tid >> 6) + 1; wv < NW; ++wv) above_waves += wtot[wv];
    unsigned int acc = (s - v) + above_waves;
    for (int bin = base + (NBINS / NT) - 1; bin >= base; --bin) {
        unsigned int cnt = hist[bin];
        if (acc < (unsigned int)target && acc + cnt >= (unsigned int)target) *s_T1 = bin;
        acc += cnt;
    }
    __syncthreads();
}

// K1 LDS: [0,8192) hist -> cand2 ; [8192,16384) cand
#define OFF_CAND   8192
#define POOL1_BYTES 16384

// ============ K1: top-300 select (per task), gather fused into rank write ============
__global__ __launch_bounds__(NT) void k_select(const float* __restrict__ in,
                                               float4* __restrict__ wsBox,
                                               float* __restrict__ wsVal,
                                               int* __restrict__ wsCnt) {
    __shared__ __align__(16) unsigned char pool[POOL1_BYTES];
    __shared__ unsigned int wtot[NW];
    __shared__ unsigned int s_cnt, s_cnt2;
    __shared__ int s_T1;

    unsigned int* hist = (unsigned int*)pool;
    ull* cand2 = (ull*)pool;
    ull* cand  = (ull*)(pool + OFF_CAND);

    const int tid = threadIdx.x;
    const int lane = tid & 63;
    const ull ltm = (1ull << lane) - 1ull;
    const int t = blockIdx.x;
    // XCD swizzle: image b -> XCD b%8
    const int b = (t & 7) + 8 * ((t >> 3) & 3);
    const int c = t >> 5;
    const float* cls = in + (size_t)b * NCH * NA + (size_t)(4 + c) * NA;
    const float* box = in + (size_t)b * NCH * NA;

    for (int i = tid; i < NBINS; i += NT) hist[i] = 0;
    if (tid == 0) { s_cnt = 0; s_cnt2 = 0; s_T1 = -1; }
    __syncthreads();

    // P1: prefilter x>1.4, wave-aggregated compaction, fused refine histogram
    {
        const float4* cls4 = (const float4*)cls;
        for (int q = tid; q < NA / 4; q += NT) {
            float4 v = cls4[q];
            const unsigned int i0 = (unsigned int)q * 4u;
            float xs[4] = {v.x, v.y, v.z, v.w};
            ull m[4];
            unsigned int cnt = 0;
#pragma unroll
            for (int u = 0; u < 4; ++u) {
                m[u] = __ballot(xs[u] > PREF_X);
                cnt += (unsigned int)__popcll(m[u]);
            }
            if (cnt) {
                unsigned int base = 0;
                if (lane == 0) base = atomicAdd(&s_cnt, cnt);
                base = (unsigned int)__builtin_amdgcn_readfirstlane((int)base);
                unsigned int pre = 0;
#pragma unroll
                for (int u = 0; u < 4; ++u) {
                    if (xs[u] > PREF_X) {
                        unsigned int mk = mono_key(__float_as_uint(xs[u]));
                        atomicAdd(&hist[min((mk - FAST_KBASE) >> FAST_SHIFT,
                                            (unsigned)(NBINS - 1))], 1u);
                        unsigned int p = base + pre + (unsigned int)__popcll(m[u] & ltm);
                        if (p < CAP)
                            cand[p] = ((ull)mk << 32) | (ull)(~(i0 + u));
                    }
                    pre += (unsigned int)__popcll(m[u]);
                }
            }
        }
    }
    __syncthreads();

    const int pcnt = (int)s_cnt;
    if (pcnt >= TARGET && pcnt <= CAP) {
        // ---- fast path ----
        suffix_find(hist, wtot, TARGET, tid, &s_T1);
        const ull thr = ((ull)FAST_KBASE + ((ull)(unsigned int)s_T1 << FAST_SHIFT)) << 32;
        const int iters = (pcnt + NT - 1) / NT;
        for (int it = 0; it < iters; ++it) {
            int e = tid + it * NT;
            bool act = e < pcnt;
            ull k = act ? cand[e] : 0ull;
            bool sel = act && (k >= thr);
            ull mb = __ballot(sel);
            unsigned int cnt = (unsigned int)__popcll(mb);
            if (cnt) {
                unsigned int basep = 0;
                if (lane == 0) basep = atomicAdd(&s_cnt2, cnt);
                basep = (unsigned int)__builtin_amdgcn_readfirstlane((int)basep);
                if (sel) {
                    float xv = __uint_as_float(mono_inv((unsigned int)(k >> 32)));
                    float sv = sigmoidf(xv);
                    unsigned int p = basep + (unsigned int)__popcll(mb & ltm);
                    if (p < CAP)
                        cand2[p] = ((ull)__float_as_uint(sv) << 32) | (k & 0xFFFFFFFFull);
                }
            }
        }
        __syncthreads();
    } else {
        // ---- exact fallback (rare): re-zero hist, full conf_pass histogram ----
        __syncthreads();
        for (int i = tid; i < NBINS; i += NT) hist[i] = 0;
        __syncthreads();
        {
            const float4* cls4 = (const float4*)cls;
            for (int q = tid; q < NA / 4; q += NT) {
                float4 v = cls4[q];
                unsigned int kx = make_key(v.x), ky = make_key(v.y);
                unsigned int kz = make_key(v.z), kw = make_key(v.w);
                if (kx) atomicAdd(&hist[min((kx - FB_KBASE) >> FB_SHIFT, (unsigned)(NBINS - 1))], 1u);
                if (ky) atomicAdd(&hist[min((ky - FB_KBASE) >> FB_SHIFT, (unsigned)(NBINS - 1))], 1u);
                if (kz) atomicAdd(&hist[min((kz - FB_KBASE) >> FB_SHIFT, (unsigned)(NBINS - 1))], 1u);
                if (kw) atomicAdd(&hist[min((kw - FB_KBASE) >> FB_SHIFT, (unsigned)(NBINS - 1))], 1u);
            }
        }
        __syncthreads();
        suffix_find(hist, wtot, TARGET, tid, &s_T1);
        {
            const ull thr = (s_T1 < 0) ? 0ull
                : ((ull)FB_KBASE + ((ull)(unsigned int)s_T1 << FB_SHIFT));
            const float4* cls4 = (const float4*)cls;
            for (int q = tid; q < NA / 4; q += NT) {
                float4 v = cls4[q];
                const unsigned int i0 = (unsigned int)q * 4u;
                float xs[4] = {v.x, v.y, v.z, v.w};
#pragma unroll
                for (int u = 0; u < 4; ++u) {
                    unsigned int d = make_key(xs[u]);
                    if (d && (ull)d >= thr) {
                        unsigned int p = atomicAdd(&s_cnt2, 1u);
                        if (p < CAP) {
                            float sv = sigmoidf(xs[u]);
                            cand2[p] = ((ull)__float_as_uint(sv) << 32) | (ull)(~(i0 + u));
                        }
                    }
                }
            }
        }
        __syncthreads();
    }

    const int F = min((int)s_cnt2, CAP);
    const int numSel = min(F, TOPK);

    // rank-by-counting (unique keys via ~idx) + FUSED box gather to ws
    float4* tBox = wsBox + (size_t)t * TOPK;
    float*  tVal = wsVal + (size_t)t * TOPK;
    for (int e = tid; e < F; e += NT) {
        ull k = cand2[e];
        int rank = 0;
        int o = 0;
#pragma unroll 2
        for (; o + 4 <= F; o += 4) {
            ulonglong2 p0 = *(const ulonglong2*)&cand2[o];
            ulonglong2 p1 = *(const ulonglong2*)&cand2[o + 2];
            rank += (p0.x > k) + (p0.y > k) + (p1.x > k) + (p1.y > k);
        }
        for (; o < F; ++o) rank += (cand2[o] > k) ? 1 : 0;
        if (rank < TOPK) {
            unsigned int i = ~(unsigned int)(k & 0xFFFFFFFFull);
            float cx = box[i];
            float cy = box[NA + i];
            float w  = box[2 * NA + i];
            float h  = box[3 * NA + i];
            float hw = w * 0.5f, hh = h * 0.5f;
            tBox[rank] = float4{cx - hw, cy - hh, cx + hw, cy + hh};
            tVal[rank] = __uint_as_float((unsigned int)(k >> 32));
        }
    }
    if (tid == 0) wsCnt[t] = numSel;
}

// ============ K2: suppression-mask build, 2880 uniform blocks ============
__global__ __launch_bounds__(256) void k_mask(const float4* __restrict__ wsBox,
                                              const int* __restrict__ wsCnt,
                                              ull* __restrict__ wsSup) {
    const int t = blockIdx.x;
    const int g = blockIdx.y;          // row group: rows [64g, 64g+64)
    const int tid = threadIdx.x;
    const int lane = tid & 63;
    const int wave = tid >> 6;

    __shared__ float4 bs[TOPK];
    __shared__ float  ar[TOPK];
    __shared__ int s_n;
    if (tid == 0) s_n = wsCnt[t];
    __syncthreads();
    const int numSel = s_n;

    const float4* tb = wsBox + (size_t)t * TOPK;
    for (int r = tid; r < TOPK; r += 256) {
        float4 v = (r < numSel) ? tb[r] : float4{0.f, 0.f, 0.f, 0.f};
        bs[r] = v;
        ar[r] = fmaxf(v.z - v.x, 0.f) * fmaxf(v.w - v.y, 0.f);
    }
    __syncthreads();

    float4 cb[5];
    float ca[5];
#pragma unroll
    for (int w = 0; w < 5; ++w) {
        int j = (w << 6) + lane;
        bool v = j < TOPK;
        cb[w] = v ? bs[j] : float4{0.f, 0.f, 0.f, 0.f};
        ca[w] = v ? ar[j] : 0.f;
    }

    const int r0 = g << 6;
    const int rend = min(r0 + 64, TOPK);
    ull* supt = wsSup + (size_t)t * (TOPK * 5);
    for (int r = r0 + wave; r < rend; r += 4) {
        const bool vrow = r < numSel;      // wave-uniform
        float4 bi = bs[r];
        float ai = ar[r];
#pragma unroll
        for (int w = 0; w < 5; ++w) {
            ull bal = 0ull;
            if (w >= g && vrow) {          // uniform branch
                const int j = (w << 6) + lane;
                bool supb = false;
                if (j < numSel && j > r) {
                    float xx1 = fmaxf(bi.x, cb[w].x);
                    float yy1 = fmaxf(bi.y, cb[w].y);
                    float xx2 = fminf(bi.z, cb[w].z);
                    float yy2 = fminf(bi.w, cb[w].w);
                    float iw = fmaxf(xx2 - xx1, 0.0f);
                    float ih = fmaxf(yy2 - yy1, 0.0f);
                    float inter = iw * ih;
                    float un = ai + ca[w] - inter;
                    float D = fmaxf(un, 1e-9f);
                    supb = (double)inter > M45 * (double)D;  // == RN(inter/D) > 0.45f
                }
                bal = __ballot(supb);
            }
            if (lane == 0) supt[r * 5 + w] = bal;
        }
    }
}

// ============ K3: greedy scan + output. The 25 mask words are PINNED into
// VGPRs with an empty asm "+v" constraint after the loads: R12 showed the
// compiler otherwise REMATERIALIZES the global loads inside the serial scan
// (VGPR_Count=32, ~500-cyc global chain per iteration -> 44 us). Post-asm the
// values are opaque -> must stay in registers; launch_bounds(64,1) gives
// headroom so they cannot spill. ====
#define PIN64(x) asm volatile("" : "+v"(x))

__global__ __launch_bounds__(64, 1) void k_scan_out(const float4* __restrict__ wsBox,
                                                    const float* __restrict__ wsVal,
                                                    const int* __restrict__ wsCnt,
                                                    const ull* __restrict__ wsSup,
                                                    float* __restrict__ out) {
    const int t = blockIdx.x;
    const int lane = threadIdx.x;
    const int numSel = wsCnt[t];
    const ull* supt = wsSup + (size_t)t * (TOPK * 5);

    // Row r = 64*w + lane holds words x=0..4. Groups 0..3 always in range
    // (r <= 255 < 300); group 4 valid iff lane < 44.
    const ull* p0 = supt + (size_t)(lane) * 5;
    ull A00 = p0[0], A01 = p0[1], A02 = p0[2], A03 = p0[3], A04 = p0[4];
    const ull* p1 = supt + (size_t)(64 + lane) * 5;
    ull A10 = p1[0], A11 = p1[1], A12 = p1[2], A13 = p1[3], A14 = p1[4];
    const ull* p2 = supt + (size_t)(128 + lane) * 5;
    ull A20 = p2[0], A21 = p2[1], A22 = p2[2], A23 = p2[3], A24 = p2[4];
    const ull* p3 = supt + (size_t)(192 + lane) * 5;
    ull A30 = p3[0], A31 = p3[1], A32 = p3[2], A33 = p3[3], A34 = p3[4];
    const bool v4 = lane < (TOPK - 256);
    const ull* p4 = supt + (size_t)(256 + (v4 ? lane : 0)) * 5;
    ull A40 = v4 ? p4[0] : 0ull, A41 = v4 ? p4[1] : 0ull, A42 = v4 ? p4[2] : 0ull,
        A43 = v4 ? p4[3] : 0ull, A44 = v4 ? p4[4] : 0ull;

    PIN64(A00); PIN64(A01); PIN64(A02); PIN64(A03); PIN64(A04);
    PIN64(A10); PIN64(A11); PIN64(A12); PIN64(A13); PIN64(A14);
    PIN64(A20); PIN64(A21); PIN64(A22); PIN64(A23); PIN64(A24);
    PIN64(A30); PIN64(A31); PIN64(A32); PIN64(A33); PIN64(A34);
    PIN64(A40); PIN64(A41); PIN64(A42); PIN64(A43); PIN64(A44);

    ull rem0 = 0, rem1 = 0, rem2 = 0, rem3 = 0, rem4 = 0;
    {
        int n = min(numSel, 64);
        for (int i = 0; i < n; ++i)
            if (!((rem0 >> i) & 1ull)) {    // uniform: rem identical on all lanes
                rem0 |= readlane64(A00, i); rem1 |= readlane64(A01, i);
                rem2 |= readlane64(A02, i); rem3 |= readlane64(A03, i);
                rem4 |= readlane64(A04, i);
            }
    }
    {
        int n = min(max(numSel - 64, 0), 64);
        for (int i = 0; i < n; ++i)
            if (!((rem1 >> i) & 1ull)) {
                rem0 |= readlane64(A10, i); rem1 |= readlane64(A11, i);
                rem2 |= readlane64(A12, i); rem3 |= readlane64(A13, i);
                rem4 |= readlane64(A14, i);
            }
    }
    {
        int n = min(max(numSel - 128, 0), 64);
        for (int i = 0; i < n; ++i)
            if (!((rem2 >> i) & 1ull)) {
                rem0 |= readlane64(A20, i); rem1 |= readlane64(A21, i);
                rem2 |= readlane64(A22, i); rem3 |= readlane64(A23, i);
                rem4 |= readlane64(A24, i);
            }
    }
    {
        int n = min(max(numSel - 192, 0), 64);
        for (int i = 0; i < n; ++i)
            if (!((rem3 >> i) & 1ull)) {
                rem0 |= readlane64(A30, i); rem1 |= readlane64(A31, i);
                rem2 |= readlane64(A32, i); rem3 |= readlane64(A33, i);
                rem4 |= readlane64(A34, i);
            }
    }
    {
        int n = min(max(numSel - 256, 0), 64);
        for (int i = 0; i < n; ++i)
            if (!((rem4 >> i) & 1ull)) {
                rem0 |= readlane64(A40, i); rem1 |= readlane64(A41, i);
                rem2 |= readlane64(A42, i); rem3 |= readlane64(A43, i);
                rem4 |= readlane64(A44, i);
            }
    }

    const int b = (t & 7) + 8 * ((t >> 3) & 3);
    const int c = t >> 5;
    float* outp = out + ((size_t)b * NC + c) * (TOPK * 6);
    const float4* tb = wsBox + (size_t)t * TOPK;
    const float* tv = wsVal + (size_t)t * TOPK;

    auto write_row = [&](int w, ull remw) {
        int r = (w << 6) + lane;
        if (r < TOPK) {
            float x1 = 0.f, y1 = 0.f, x2 = 0.f, y2 = 0.f, vv = 0.f, cc = 0.f;
            if (r < numSel && ((~remw >> lane) & 1ull)) {
                float4 bb = tb[r];
                x1 = bb.x; y1 = bb.y; x2 = bb.z; y2 = bb.w;
                vv = tv[r]; cc = (float)c;
            }
            float* row = outp + r * 6;
            *(float2*)(row)     = float2{x1, y1};
            *(float2*)(row + 2) = float2{x2, y2};
            *(float2*)(row + 4) = float2{vv, cc};
        }
    };
    write_row(0, rem0);
    write_row(1, rem1);
    write_row(2, rem2);
    write_row(3, rem3);
    write_row(4, rem4);
}

extern "C" void kernel_launch(void* const* d_in, const int* in_sizes, int n_in,
                              void* d_out, int out_size, void* d_ws, size_t ws_size,
                              hipStream_t stream) {
    const float* in = (const float*)d_in[0];
    float* out = (float*)d_out;
    char* ws = (char*)d_ws;
    float4* wsBox = (float4*)(ws + WS_BOX);
    float*  wsVal = (float*)(ws + WS_VAL);
    ull*    wsSup = (ull*)(ws + WS_SUP);
    int*    wsCnt = (int*)(ws + WS_CNT);

    k_select<<<NTASK, NT, 0, stream>>>(in, wsBox, wsVal, wsCnt);
    k_mask<<<dim3(NTASK, 5), 256, 0, stream>>>(wsBox, wsCnt, wsSup);
    k_scan_out<<<NTASK, 64, 0, stream>>>(wsBox, wsVal, wsCnt, wsSup, out);
}